// Round 10
// baseline (1006.062 us; speedup 1.0000x reference)
//
#include <hip/hip_runtime.h>
#include <math.h>

typedef unsigned short u16;
typedef u16 u16x8 __attribute__((ext_vector_type(8)));
typedef __bf16 bf16x8 __attribute__((ext_vector_type(8)));
typedef float f32x4 __attribute__((ext_vector_type(4)));

#define HID 200
#define G4H 800
#define TLEN 128
#define LATENT 128
#define NCODES 1024
#define DIN 768
#define DCOND 1536
#define NB 256
#define MROWS (NB * TLEN)
#define LDG 896
#define LDH1 256
#define LDH2 512
#define NOUT 768

__device__ __forceinline__ u16 f2b(float f) {
  union { float f; unsigned u; } v; v.f = f;
  unsigned r = v.u + 0x7fffu + ((v.u >> 16) & 1u);
  return (u16)(r >> 16);
}
__device__ __forceinline__ float b2f(u16 h) {
  union { unsigned u; float f; } v; v.u = ((unsigned)h) << 16;
  return v.f;
}
__device__ __forceinline__ float sigf(float x) { return 1.f / (1.f + __expf(-x)); }
__device__ __forceinline__ float tanh_fast(float x) {
  return 1.f - 2.f / (__expf(2.f * x) + 1.f);
}

// async global->LDS, 16B per lane
__device__ __forceinline__ void gl16(const void* g, void* l) {
  __builtin_amdgcn_global_load_lds(
      (const __attribute__((address_space(1))) void*)g,
      (__attribute__((address_space(3))) void*)l, 16, 0, 0);
}

__device__ __forceinline__ unsigned cvtpk(float a, float b) {
  unsigned r;
  asm("v_cvt_pk_bf16_f32 %0, %1, %2" : "=v"(r) : "v"(a), "v"(b));
  return r;
}

// unpack 4 bf16 (as uint2) -> f32x4
__device__ __forceinline__ f32x4 gx4(uint2 u) {
  union { unsigned q; float f; } a;
  f32x4 r;
  a.q = u.x << 16;          r.x = a.f;
  a.q = u.x & 0xFFFF0000u;  r.y = a.f;
  a.q = u.y << 16;          r.z = a.f;
  a.q = u.y & 0xFFFF0000u;  r.w = a.f;
  return r;
}

// ---------------- weight convert + pad ----------------
__global__ void cvt_pad(const float* __restrict__ src, u16* __restrict__ dst,
                        int nr, int nc, int lds, int col0, int NRp, int KP) {
  int i = blockIdx.x * blockDim.x + threadIdx.x;
  if (i >= NRp * KP) return;
  int r = i / KP, c = i - r * KP;
  float v = (r < nr && c < nc) ? src[(size_t)r * lds + col0 + c] : 0.f;
  dst[i] = f2b(v);
}

__global__ void pad_f32(const float* __restrict__ src, float* __restrict__ dst,
                        int n, int npad) {
  int i = blockIdx.x * blockDim.x + threadIdx.x;
  if (i < npad) dst[i] = (i < n) ? src[i] : 0.f;
}

// biasc[col<896] = b_ih + b_hh (0-padded)
__global__ void bias_pack(const float* __restrict__ b_ih, const float* __restrict__ b_hh,
                          float* __restrict__ biasc) {
  int i = blockIdx.x * blockDim.x + threadIdx.x;
  if (i < LDG) biasc[i] = (i < G4H) ? (b_ih[i] + b_hh[i]) : 0.f;
}

// W_hh [800][200] f32 -> MFMA A-fragments, bf16.
// Wf[((w*8+tt)*7+f)*64 + l] = uint4 of 8 bf16:
//   tile tt: gate = tt>>1, s = tt&1; row u = w*32 + s*16 + (l&15) (pad>=200 -> 0)
//   k = f*32 + (l>>4)*8 + 2d+{0,1} (pad>=200 -> 0); real W row = gate*200 + u.
__global__ void pack_wf(const float* __restrict__ Whh, uint4* __restrict__ Wf) {
  int i = blockIdx.x * blockDim.x + threadIdx.x;
  if (i >= 56 * 64) return;
  int l = i & 63, rest = i >> 6;
  int f = rest % 7, tt = (rest / 7) & 7, w = rest / 56;
  int gate = tt >> 1, s = tt & 1;
  int u = w * 32 + s * 16 + (l & 15);
  int kbase = f * 32 + (l >> 4) * 8;
  unsigned out[4];
#pragma unroll
  for (int d = 0; d < 4; ++d) {
    unsigned lo = 0, hi = 0;
    int k0 = kbase + 2 * d, k1 = k0 + 1;
    if (u < HID) {
      const float* row = Whh + (size_t)(gate * HID + u) * HID;
      if (k0 < HID) lo = f2b(row[k0]);
      if (k1 < HID) hi = f2b(row[k1]);
    }
    out[d] = lo | (hi << 16);
  }
  uint4 o; o.x = out[0]; o.y = out[1]; o.z = out[2]; o.w = out[3];
  Wf[i] = o;
}

// ---------------- bf16 MFMA GEMM: C[M,N] = A[M,K] * B[N,K]^T (+epilogue) ----------------
enum { EPI_GATES = 0, EPI_H1 = 1, EPI_H2 = 2, EPI_OUT = 3 };

__device__ __forceinline__ f32x4 mfma16(bf16x8 a, bf16x8 b, f32x4 c) {
  return __builtin_amdgcn_mfma_f32_16x16x32_bf16(a, b, c, 0, 0, 0);
}

template<bool AF32, int EPI>
__global__ __launch_bounds__(256) void gemm_bf16(
    const void* __restrict__ Ap, const u16* __restrict__ Bp,
    void* __restrict__ Cp, int K, int ldc, const float* __restrict__ bias) {
  __shared__ __attribute__((aligned(16))) char AsRaw[AF32 ? 128 * 32 * 4 : 128 * 32 * 2];
  __shared__ __attribute__((aligned(16))) u16 Bs[128 * 32];
  float* Asf = (float*)AsRaw;
  u16* As16 = (u16*)AsRaw;

  const int t = threadIdx.x;
  const int tileN = blockIdx.x * 128;
  const int tileM = blockIdx.y * 128;
  const int l = t & 63;
  const int w = t >> 6;
  const int wr = (w >> 1) * 64;
  const int wc = (w & 1) * 64;
  const int fr = l & 15;
  const int fg = l >> 4;

  const u16* bsrc[2];
  u16* bdst[2];
#pragma unroll
  for (int j = 0; j < 2; ++j) {
    int tb = w * 1024 + j * 4096 + (t & 63) * 16;
    int row = tb >> 6, gd = (tb >> 4) & 3;
    bsrc[j] = Bp + (size_t)(tileN + row) * K + ((gd ^ ((row >> 1) & 3)) << 3);
    bdst[j] = Bs + w * 512 + j * 2048;
  }
  const float* asrcF[4];
  float* adstF[4];
  const u16* asrcH[2];
  u16* adstH[2];
  if constexpr (AF32) {
#pragma unroll
    for (int j = 0; j < 4; ++j) {
      int tb = w * 1024 + j * 4096 + (t & 63) * 16;
      int row = tb >> 7, gd = (tb >> 4) & 7;
      asrcF[j] = (const float*)Ap + (size_t)(tileM + row) * K + ((gd ^ (row & 7)) << 2);
      adstF[j] = Asf + w * 256 + j * 1024;
    }
  } else {
#pragma unroll
    for (int j = 0; j < 2; ++j) {
      int tb = w * 1024 + j * 4096 + (t & 63) * 16;
      int row = tb >> 6, gd = (tb >> 4) & 3;
      asrcH[j] = (const u16*)Ap + (size_t)(tileM + row) * K + ((gd ^ ((row >> 1) & 3)) << 3);
      adstH[j] = As16 + w * 512 + j * 2048;
    }
  }

  f32x4 acc[4][4];
#pragma unroll
  for (int m = 0; m < 4; ++m)
#pragma unroll
    for (int n = 0; n < 4; ++n) {
      f32x4 z = {0.f, 0.f, 0.f, 0.f};
      acc[m][n] = z;
    }

  for (int k0 = 0; k0 < K; k0 += 32) {
#pragma unroll
    for (int j = 0; j < 2; ++j) { gl16(bsrc[j], bdst[j]); bsrc[j] += 32; }
    if constexpr (AF32) {
#pragma unroll
      for (int j = 0; j < 4; ++j) { gl16(asrcF[j], adstF[j]); asrcF[j] += 32; }
    } else {
#pragma unroll
      for (int j = 0; j < 2; ++j) { gl16(asrcH[j], adstH[j]); asrcH[j] += 32; }
    }
    __syncthreads();

    bf16x8 av[4], bv[4];
#pragma unroll
    for (int m = 0; m < 4; ++m) {
      const int row = wr + m * 16 + fr;
      if constexpr (AF32) {
        const int g0 = (2 * fg) ^ (row & 7);
        const int g1 = (2 * fg + 1) ^ (row & 7);
        float4 p0 = *(const float4*)(Asf + row * 32 + g0 * 4);
        float4 p1 = *(const float4*)(Asf + row * 32 + g1 * 4);
        uint4 u;
        u.x = cvtpk(p0.x, p0.y); u.y = cvtpk(p0.z, p0.w);
        u.z = cvtpk(p1.x, p1.y); u.w = cvtpk(p1.z, p1.w);
        av[m] = __builtin_bit_cast(bf16x8, u);
      } else {
        const int g = fg ^ ((row >> 1) & 3);
        av[m] = __builtin_bit_cast(bf16x8, *(const u16x8*)(As16 + row * 32 + g * 8));
      }
    }
#pragma unroll
    for (int n = 0; n < 4; ++n) {
      const int row = wc + n * 16 + fr;
      const int g = fg ^ ((row >> 1) & 3);
      bv[n] = __builtin_bit_cast(bf16x8, *(const u16x8*)(Bs + row * 32 + g * 8));
    }
#pragma unroll
    for (int m = 0; m < 4; ++m)
#pragma unroll
      for (int n = 0; n < 4; ++n)
        acc[m][n] = mfma16(av[m], bv[n], acc[m][n]);
    __syncthreads();
  }

#pragma unroll
  for (int m = 0; m < 4; ++m) {
#pragma unroll
    for (int n = 0; n < 4; ++n) {
      const int gcol = tileN + wc + n * 16 + fr;
      const int growb = tileM + wr + m * 16 + fg * 4;
#pragma unroll
      for (int r = 0; r < 4; ++r) {
        const int grow = growb + r;
        float v = acc[m][n][r];
        if constexpr (EPI == EPI_GATES) {
          // write gates to [t][b][r'] frag-friendly layout, bias folded.
          v += bias[gcol];
          int tt = grow & 127, bb = grow >> 7;
          int rp;
          if (gcol < G4H) rp = (gcol / HID) * 224 + gcol % HID;
          else { int j = gcol - G4H; rp = (j / 24) * 224 + 200 + j % 24; }
          ((u16*)Cp)[((size_t)tt * 256 + bb) * LDG + rp] = f2b(v);
        } else if constexpr (EPI == EPI_H1) {
          v += bias[(grow >> 7) * 256 + gcol];
          v = fmaxf(v, 0.f);
          ((u16*)Cp)[(size_t)grow * ldc + gcol] = f2b(v);
        } else if constexpr (EPI == EPI_H2) {
          v += bias[gcol];
          v = fmaxf(v, 0.f);
          ((u16*)Cp)[(size_t)grow * ldc + gcol] = f2b(v);
        } else {
          v += bias[gcol];
          ((float*)Cp)[(size_t)grow * ldc + gcol] = sigf(v);
        }
      }
    }
  }
}

// ---------------- MFMA LSTM scan ----------------
// 16 blocks x 16 batches, 448 threads (7 waves). W_hh register-resident as
// 56 bf16x8 MFMA A-frags per lane (loaded once; mfma-only use -> AGPR-eligible
// on gfx950 unified RF). Wave w owns units [32w,32w+32): all 4 gates of a unit
// land in the same lane (D: col=batch=l&15, row=fg*4+reg) -> lane-local
// activation, c in regs. h flows through a 2x7KB LDS frag buffer.
__global__ __launch_bounds__(448) void lstm_scan(
    const u16* __restrict__ gatesT,   // [128][256][896] bf16
    const uint4* __restrict__ Wf,     // frag-packed W_hh
    float* __restrict__ h_final) {    // [256][200]
  __shared__ __attribute__((aligned(16))) uint4 hbuf[2][7][64];
  const int tid = threadIdx.x;
  const int l = tid & 63;
  const int w = tid >> 6;
  const int fg = l >> 4;
  const int fr = l & 15;
  const int bglob = blockIdx.x * 16 + fr;

  // load W frags (coalesced, once)
  bf16x8 wf[8][7];
  {
    const uint4* wp = Wf + (size_t)w * 56 * 64 + l;
#pragma unroll
    for (int tt = 0; tt < 8; ++tt)
#pragma unroll
      for (int f = 0; f < 7; ++f)
        wf[tt][f] = __builtin_bit_cast(bf16x8, wp[(tt * 7 + f) * 64]);
  }
  // zero h(0) buffer
  for (int i = tid; i < 7 * 64; i += 448) {
    uint4 z = {0, 0, 0, 0};
    hbuf[0][i >> 6][i & 63] = z;
  }
  float c[8];
#pragma unroll
  for (int i = 0; i < 8; ++i) c[i] = 0.f;
  float hfin[8];

  // gate-x pointer for this lane (t advances by +256*896 elems)
  const u16* gp = gatesT + ((size_t)0 * 256 + bglob) * LDG + w * 32 + fg * 4;
  uint2 gx[8];
#pragma unroll
  for (int tt = 0; tt < 8; ++tt)
    gx[tt] = *(const uint2*)(gp + (tt >> 1) * 224 + (tt & 1) * 16);
  __syncthreads();

  for (int t = 0; t < TLEN; ++t) {
    const int cur = t & 1, nxt = cur ^ 1;
    // prefetch next step's gate-x
    uint2 gxn[8];
    gp += 256 * LDG;
    if (t + 1 < TLEN) {
#pragma unroll
      for (int tt = 0; tt < 8; ++tt)
        gxn[tt] = *(const uint2*)(gp + (tt >> 1) * 224 + (tt & 1) * 16);
    }
    // read h frags
    bf16x8 hf[7];
#pragma unroll
    for (int f = 0; f < 7; ++f)
      hf[f] = __builtin_bit_cast(bf16x8, hbuf[cur][f][l]);
    // gates = x-part + W_hh @ h
    f32x4 acc[8];
#pragma unroll
    for (int tt = 0; tt < 8; ++tt) acc[tt] = gx4(gx[tt]);
#pragma unroll
    for (int f = 0; f < 7; ++f)
#pragma unroll
      for (int tt = 0; tt < 8; ++tt)
        acc[tt] = mfma16(wf[tt][f], hf[f], acc[tt]);
    // activation (lane-local) + write h(t+1) frags
#pragma unroll
    for (int s = 0; s < 2; ++s) {
      float hh[4];
#pragma unroll
      for (int reg = 0; reg < 4; ++reg) {
        float gi = acc[0 + s][reg], gf = acc[2 + s][reg];
        float gg = acc[4 + s][reg], go = acc[6 + s][reg];
        int ci = s * 4 + reg;
        c[ci] = sigf(gf) * c[ci] + sigf(gi) * tanh_fast(gg);
        float h = sigf(go) * tanh_fast(c[ci]);
        int u = w * 32 + s * 16 + fg * 4 + reg;
        hh[reg] = (u < HID) ? h : 0.f;
        hfin[ci] = hh[reg];
      }
      uint2 pk;
      pk.x = cvtpk(hh[0], hh[1]);
      pk.y = cvtpk(hh[2], hh[3]);
      const int g = s * 2 + (fg >> 1);
      *(uint2*)((char*)&hbuf[nxt][w][0] + (g * 16 + fr) * 16 + (fg & 1) * 8) = pk;
    }
#pragma unroll
    for (int tt = 0; tt < 8; ++tt) gx[tt] = gxn[tt];
    __syncthreads();
  }

  // final h -> global
#pragma unroll
  for (int s = 0; s < 2; ++s)
#pragma unroll
    for (int reg = 0; reg < 4; ++reg) {
      int u = w * 32 + s * 16 + fg * 4 + reg;
      if (u < HID) h_final[(size_t)bglob * HID + u] = hfin[s * 4 + reg];
    }
}

// ---------------- encoder + VQ + p1 (one block per batch) ----------------
__global__ __launch_bounds__(256) void enc_vq(
    const float* __restrict__ h_final,
    const float* __restrict__ Wenc, const float* __restrict__ b_enc,
    const float* __restrict__ emb, const float* __restrict__ W1,
    const float* __restrict__ b1, const float* __restrict__ noise,
    float* __restrict__ p1) {
  __shared__ __attribute__((aligned(16))) float sh_hf[HID];
  __shared__ __attribute__((aligned(16))) float sh_ze[LATENT];
  __shared__ float sh_zq[LATENT];
  __shared__ float sh_rd[256];
  __shared__ int sh_ri[256];
  const int r = threadIdx.x;
  const int b = blockIdx.x;

  if (r < HID) sh_hf[r] = h_final[(size_t)b * HID + r];
  __syncthreads();

  if (r < LATENT) {
    float z = b_enc[r];
#pragma unroll 4
    for (int k = 0; k < HID; ++k) z = fmaf(Wenc[(size_t)r * HID + k], sh_hf[k], z);
    sh_ze[r] = z;
  }
  __syncthreads();

  float best = INFINITY; int bi = 0;
  for (int k = r; k < NCODES; k += 256) {
    float d = 0.f;
#pragma unroll
    for (int q = 0; q < LATENT / 4; ++q) {
      float4 e = *(const float4*)&emb[(size_t)k * LATENT + q * 4];
      float4 z = *(const float4*)&sh_ze[q * 4];
      d += e.x * (e.x - 2.f * z.x) + e.y * (e.y - 2.f * z.y)
         + e.z * (e.z - 2.f * z.z) + e.w * (e.w - 2.f * z.w);
    }
    if (d < best) { best = d; bi = k; }
  }
  sh_rd[r] = best; sh_ri[r] = bi;
  __syncthreads();
  for (int s = 128; s > 0; s >>= 1) {
    if (r < s) {
      float od = sh_rd[r + s]; int oi = sh_ri[r + s];
      if (od < sh_rd[r] || (od == sh_rd[r] && oi < sh_ri[r])) { sh_rd[r] = od; sh_ri[r] = oi; }
    }
    __syncthreads();
  }
  const int kmin = sh_ri[0];
  if (r < LATENT) sh_zq[r] = emb[(size_t)kmin * LATENT + r];
  __syncthreads();

  // p1[b][j] = b1 + W1[:,0:128].zq + W1[:,1664:2432].noise (pad 200..255 = 0)
  float v = 0.f;
  if (r < HID) {
    v = b1[r];
    const float* wrow = W1 + (size_t)r * 2432;
#pragma unroll 4
    for (int d = 0; d < LATENT; ++d) v = fmaf(wrow[d], sh_zq[d], v);
    const float* nz = noise + (size_t)b * DIN;
#pragma unroll 4
    for (int d = 0; d < DIN; ++d) v = fmaf(wrow[1664 + d], nz[d], v);
  }
  p1[b * 256 + r] = v;
}

// ---------------- host ----------------
extern "C" void kernel_launch(void* const* d_in, const int* in_sizes, int n_in,
                              void* d_out, int out_size, void* d_ws, size_t ws_size,
                              hipStream_t stream) {
  const float* x     = (const float*)d_in[0];
  const float* cond  = (const float*)d_in[1];
  const float* noise = (const float*)d_in[2];
  const float* W_ih  = (const float*)d_in[3];
  const float* W_hh  = (const float*)d_in[4];
  const float* b_ih  = (const float*)d_in[5];
  const float* b_hh  = (const float*)d_in[6];
  const float* W_enc = (const float*)d_in[7];
  const float* b_enc = (const float*)d_in[8];
  const float* emb   = (const float*)d_in[9];
  const float* W1    = (const float*)d_in[10];
  const float* b1    = (const float*)d_in[11];
  const float* W2    = (const float*)d_in[12];
  const float* b2    = (const float*)d_in[13];
  const float* W3    = (const float*)d_in[14];
  const float* b3    = (const float*)d_in[15];

  char* ws = (char*)d_ws;
  size_t off = 0;
  auto alloc = [&](size_t bytes) -> void* {
    void* p = ws + off; off += (bytes + 255) & ~(size_t)255; return p;
  };
  u16*   W_ihb = (u16*)alloc((size_t)896 * 768 * 2);
  u16*   W1cb  = (u16*)alloc((size_t)256 * 1536 * 2);
  u16*   W2b   = (u16*)alloc((size_t)512 * 256 * 2);
  u16*   W3b   = (u16*)alloc((size_t)768 * 512 * 2);
  float* b2p   = (float*)alloc(512 * 4);
  uint4* Wf    = (uint4*)alloc((size_t)56 * 64 * 16);
  float* biasc = (float*)alloc(LDG * 4);
  u16*   gatesT = (u16*)alloc((size_t)MROWS * LDG * 2);   // [t][b][r']
  float* h_fin = (float*)alloc((size_t)NB * HID * 4);
  float* p1    = (float*)alloc(256 * 256 * 4);
  u16*   h1    = (u16*)alloc((size_t)MROWS * LDH1 * 2);
  u16*   h2    = (u16*)alloc((size_t)MROWS * LDH2 * 2);

  cvt_pad<<<dim3((896 * 768 + 255) / 256), 256, 0, stream>>>(W_ih, W_ihb, 800, 768, 768, 0, 896, 768);
  cvt_pad<<<dim3((256 * 1536 + 255) / 256), 256, 0, stream>>>(W1, W1cb, 200, 1536, 2432, 128, 256, 1536);
  cvt_pad<<<dim3((512 * 256 + 255) / 256), 256, 0, stream>>>(W2, W2b, 400, 200, 200, 0, 512, 256);
  cvt_pad<<<dim3((768 * 512 + 255) / 256), 256, 0, stream>>>(W3, W3b, 768, 400, 400, 0, 768, 512);
  pad_f32<<<dim3(2), 256, 0, stream>>>(b2, b2p, 400, 512);
  bias_pack<<<dim3(4), 256, 0, stream>>>(b_ih, b_hh, biasc);
  pack_wf<<<dim3(14), 256, 0, stream>>>(W_hh, Wf);

  // gates = x @ W_ih^T + (b_ih+b_hh), written to [t][b][r'] bf16
  gemm_bf16<true, EPI_GATES><<<dim3(LDG / 128, MROWS / 128), 256, 0, stream>>>(
      x, W_ihb, gatesT, 768, LDG, biasc);

  // MFMA LSTM scan (16 blocks x 16 batches)
  lstm_scan<<<dim3(16), 448, 0, stream>>>(gatesT, Wf, h_fin);

  // encoder + VQ + p1
  enc_vq<<<dim3(NB), 256, 0, stream>>>(h_fin, W_enc, b_enc, emb, W1, b1, noise, p1);

  // h1 = relu(cond @ W1c^T + p1[b])
  gemm_bf16<true, EPI_H1><<<dim3(LDH1 / 128, MROWS / 128), 256, 0, stream>>>(
      cond, W1cb, h1, DCOND, LDH1, p1);
  // h2 = relu(h1 @ W2^T + b2)
  gemm_bf16<false, EPI_H2><<<dim3(LDH2 / 128, MROWS / 128), 256, 0, stream>>>(
      h1, W2b, h2, LDH1, LDH2, b2p);
  // out = sigmoid(h2 @ W3^T + b3)
  gemm_bf16<false, EPI_OUT><<<dim3(NOUT / 128, MROWS / 128), 256, 0, stream>>>(
      h2, W3b, (float*)d_out, LDH2, NOUT, b3);
}